// Round 2
// baseline (127.943 us; speedup 1.0000x reference)
//
#include <hip/hip_runtime.h>

#define N_VOX 32768
#define CCH 128
#define EPSV 1e-5f

typedef __attribute__((ext_vector_type(8))) short bfrag;
typedef __attribute__((ext_vector_type(4))) float ffrag;
typedef __attribute__((ext_vector_type(2))) unsigned int u32x2;

__device__ __forceinline__ float bf2f(unsigned short u) {
    union { unsigned int i; float f; } c; c.i = ((unsigned int)u) << 16; return c.f;
}
__device__ __forceinline__ unsigned short f2bf(float f) {
    union { float f; unsigned int i; } c; c.f = f;
    unsigned int i = c.i;
    return (unsigned short)((i + 0x7FFFu + ((i >> 16) & 1u)) >> 16);
}

// -------- Kernel 1: fused LayerNorm + QKV GEMM --------
// Block = 64 voxels. LN in registers (coalesced x loads, LDS cross-wave reduce),
// normalized bf16 tile written straight into the GEMM A-tile (no h round-trip).
// blockIdx.x = o-group (3 o-tiles each), blockIdx.y = voxel tile (adjacent
// blocks share x reads -> L2). Q outputs pre-scaled by 32^-0.5.
__global__ __launch_bounds__(256) void ln_qkv(const float* __restrict__ x,
                                              const float* __restrict__ gamma,
                                              const float* __restrict__ beta,
                                              const float* __restrict__ w,
                                              const float* __restrict__ bias,
                                              unsigned short* __restrict__ qkv) {
    __shared__ __align__(16) unsigned short a_s[64 * 136];
    __shared__ __align__(16) unsigned short b_s[64 * 136];
    __shared__ float ps[256], pq[256];
    __shared__ float muS[64], rsS[64];
    __shared__ float g[128], bta[128];
    int t = threadIdx.x;
    int og = blockIdx.x;            // o-group: tiles og*192 .. og*192+191
    int v0 = blockIdx.y * 64;
    if (t < 128) { g[t] = gamma[t]; bta[t] = beta[t]; }
    int cq = t >> 6, v = t & 63;
    // ---- LN phase: each wave owns 32 channels, all 64 voxels ----
    float xr[32];
    float s = 0.f, sq = 0.f;
    #pragma unroll
    for (int i = 0; i < 32; i++) {
        float val = x[(size_t)(cq * 32 + i) * N_VOX + v0 + v];
        xr[i] = val; s += val; sq += val * val;
    }
    ps[t] = s; pq[t] = sq;
    __syncthreads();
    if (t < 64) {
        float S = ps[t] + ps[t + 64] + ps[t + 128] + ps[t + 192];
        float Q = pq[t] + pq[t + 64] + pq[t + 128] + pq[t + 192];
        float mu = S * (1.0f / 128.0f);
        float var = Q * (1.0f / 128.0f) - mu * mu;
        muS[t] = mu; rsS[t] = rsqrtf(var + EPSV);
    }
    __syncthreads();
    {
        float mu = muS[v], rs = rsS[v];
        #pragma unroll
        for (int i8 = 0; i8 < 4; i8++) {
            union { unsigned short u[8]; uint4 q; } pk;
            #pragma unroll
            for (int k = 0; k < 8; k++) {
                int c = cq * 32 + i8 * 8 + k;
                pk.u[k] = f2bf((xr[i8 * 8 + k] - mu) * rs * g[c] + bta[c]);
            }
            *(uint4*)&a_s[v * 136 + cq * 32 + i8 * 8] = pk.q;
        }
    }
    __syncthreads();
    // ---- GEMM phase: 3 o-tiles of 64 ----
    int lane = t & 63, wvi = t >> 6, m = lane & 15, quad = lane >> 4;
    bfrag areg[4];
    #pragma unroll
    for (int kk = 0; kk < 4; kk++)
        areg[kk] = *(bfrag*)&a_s[(wvi * 16 + m) * 136 + kk * 32 + quad * 8];
    for (int t0 = 0; t0 < 3; t0++) {
        int o0 = og * 192 + t0 * 64;
        {
            int r4 = t >> 4, c8 = t & 15;
            #pragma unroll
            for (int pass = 0; pass < 4; pass++) {
                int r = pass * 16 + r4;
                float4 w0 = *(const float4*)&w[(size_t)(o0 + r) * 128 + c8 * 8];
                float4 w1 = *(const float4*)&w[(size_t)(o0 + r) * 128 + c8 * 8 + 4];
                union { unsigned short u[8]; uint4 q; } pk;
                pk.u[0] = f2bf(w0.x); pk.u[1] = f2bf(w0.y);
                pk.u[2] = f2bf(w0.z); pk.u[3] = f2bf(w0.w);
                pk.u[4] = f2bf(w1.x); pk.u[5] = f2bf(w1.y);
                pk.u[6] = f2bf(w1.z); pk.u[7] = f2bf(w1.w);
                *(uint4*)&b_s[r * 136 + c8 * 8] = pk.q;
            }
        }
        __syncthreads();
        ffrag acc[4] = {ffrag{0,0,0,0}, ffrag{0,0,0,0}, ffrag{0,0,0,0}, ffrag{0,0,0,0}};
        #pragma unroll
        for (int kk = 0; kk < 4; kk++) {
            #pragma unroll
            for (int nt = 0; nt < 4; nt++) {
                bfrag bb = *(bfrag*)&b_s[(nt * 16 + m) * 136 + kk * 32 + quad * 8];
                acc[nt] = __builtin_amdgcn_mfma_f32_16x16x32_bf16(areg[kk], bb, acc[nt], 0, 0, 0);
            }
        }
        bool isq = (o0 < 128);
        #pragma unroll
        for (int nt = 0; nt < 4; nt++) {
            int o = o0 + nt * 16 + m;
            float bs = bias[o];
            int sec = o >> 7;
            int oc = o & 127;
            unsigned short* dst = qkv + (size_t)sec * ((size_t)N_VOX * 128);
            #pragma unroll
            for (int r = 0; r < 4; r++) {
                int vg = v0 + wvi * 16 + quad * 4 + r;
                float val = acc[nt][r] + bs;
                if (isq) val *= 0.17677669529663687f;
                dst[(size_t)vg * 128 + oc] = f2bf(val);
            }
        }
        __syncthreads();
    }
}

// -------- Kernel 2: fused neighborhood attention + proj + residual --------
// Attention identical to verified round-1 structure. Then O^T accumulator
// fragments (after *inv + bf16 convert) ARE the B-operand of
// v_mfma_f32_16x16x16_bf16 (col=v, k=4*quad+e). Cross-wave exchange of the
// 4KB of O fragments through LDS (overlaid on dead V^T buffer), then each
// wave computes 32 output channels of proj over all 128 cin, and the
// epilogue adds bias + residual and stores transposed (C,N) fp32.
#define VT_STRIDE 188
__global__ __launch_bounds__(256) void attn_proj(const unsigned short* __restrict__ qb,
                                                 const unsigned short* __restrict__ kb,
                                                 const unsigned short* __restrict__ vb,
                                                 const float* __restrict__ pw,
                                                 const float* __restrict__ pbias,
                                                 const float* __restrict__ xres,
                                                 float* __restrict__ out) {
    __shared__ unsigned int vjtab[176];                      // region idx -> voxel idx
    __shared__ __align__(16) unsigned short vt[4][32 * VT_STRIDE];  // per-head V^T slice
    unsigned int* os = (unsigned int*)&vt[0][0];             // overlay: O-frag exchange

    int t = threadIdx.x;
    int bidx = blockIdx.x;
    int zh = bidx & 1, yy = (bidx >> 1) & 31, xx = bidx >> 6;
    int z0 = zh << 4;
    int sx = min(max(xx - 1, 0), 29);
    int sy = min(max(yy - 1, 0), 29);
    int zr0 = min(max(z0 - 1, 0), 14);
    int vox0 = (xx << 10) + (yy << 5) + z0;

    if (t < 176) {
        int r = t < 162 ? t : 161;
        int rxy = r / 18;
        int rzv = r - rxy * 18;
        int ax = rxy / 3;
        int by = rxy - ax * 3;
        vjtab[t] = (unsigned)(((sx + ax) << 10) + ((sy + by) << 5) + (zr0 + rzv));
    }
    __syncthreads();

    int wave = t >> 6, lane = t & 63;
    int hq = lane >> 4;
    int m = lane & 15;
    int ch0 = wave * 32;

    // ---- stage V^T slice for this head ----
    unsigned short* vts = &vt[wave][0];
    {
        const int cp = m;
        #pragma unroll
        for (int u = 0; u < 11; u++) {
            int rb = u * 16 + hq * 4;
            unsigned int j0 = vjtab[rb + 0];
            unsigned int j1 = vjtab[rb + 1];
            unsigned int j2 = vjtab[rb + 2];
            unsigned int j3 = vjtab[rb + 3];
            unsigned int d0 = *(const unsigned int*)&vb[(size_t)j0 * 128 + ch0 + cp * 2];
            unsigned int d1 = *(const unsigned int*)&vb[(size_t)j1 * 128 + ch0 + cp * 2];
            unsigned int d2 = *(const unsigned int*)&vb[(size_t)j2 * 128 + ch0 + cp * 2];
            unsigned int d3 = *(const unsigned int*)&vb[(size_t)j3 * 128 + ch0 + cp * 2];
            if (u == 10) {
                if (rb + 0 >= 162) d0 = 0u;
                if (rb + 1 >= 162) d1 = 0u;
                if (rb + 2 >= 162) d2 = 0u;
                if (rb + 3 >= 162) d3 = 0u;
            }
            unsigned int lo01 = __builtin_amdgcn_perm(d1, d0, 0x05040100u);
            unsigned int lo23 = __builtin_amdgcn_perm(d3, d2, 0x05040100u);
            unsigned int hi01 = __builtin_amdgcn_perm(d1, d0, 0x07060302u);
            unsigned int hi23 = __builtin_amdgcn_perm(d3, d2, 0x07060302u);
            u32x2 wlo; wlo.x = lo01; wlo.y = lo23;
            u32x2 whi; whi.x = hi01; whi.y = hi23;
            *(u32x2*)&vts[(2 * cp) * VT_STRIDE + rb] = wlo;
            *(u32x2*)&vts[(2 * cp + 1) * VT_STRIDE + rb] = whi;
        }
    }

    // ---- QK^T (swapped): S^T[r][v], Q pre-scaled ----
    bfrag qf = *(const bfrag*)&qb[(size_t)(vox0 + m) * 128 + ch0 + hq * 8];
    ffrag s[11];
    #pragma unroll
    for (int f = 0; f < 11; f++) {
        unsigned int vj = vjtab[f * 16 + m];
        bfrag kf = *(const bfrag*)&kb[(size_t)vj * 128 + ch0 + hq * 8];
        s[f] = __builtin_amdgcn_mfma_f32_16x16x32_bf16(kf, qf, ffrag{0,0,0,0}, 0, 0, 0);
    }

    // ---- mask + softmax (per voxel v = lane&15, 4-lane chunks over r) ----
    int zv = z0 + m;
    int szv = min(max(zv - 1, 0), 29);
    unsigned int wz = (unsigned int)(szv - zr0);
    unsigned int rz = 4u * (unsigned int)hq;
    float mx = -1e30f;
    #pragma unroll
    for (int f = 0; f < 11; f++) {
        #pragma unroll
        for (int i = 0; i < 4; i++) {
            unsigned int ri = rz + (unsigned int)i;
            ri = min(ri, ri - 18u);
            bool valid = (ri - wz) <= 2u;
            if (f == 10) valid = valid && ((4 * hq + i) < 2);
            float sv = valid ? s[f][i] : -1e30f;
            s[f][i] = sv;
            mx = fmaxf(mx, sv);
        }
        rz = min(rz + 16u, rz - 2u);
    }
    mx = fmaxf(mx, __shfl_xor(mx, 16));
    mx = fmaxf(mx, __shfl_xor(mx, 32));
    float sum = 0.f;
    #pragma unroll
    for (int f = 0; f < 11; f++) {
        #pragma unroll
        for (int i = 0; i < 4; i++) {
            float p = __expf(s[f][i] - mx);
            s[f][i] = p;
            sum += p;
        }
    }
    sum += __shfl_xor(sum, 16);
    sum += __shfl_xor(sum, 32);
    float inv = 1.0f / sum;

    // ---- PV: O^T = V^T . P^T, P from regs ----
    ffrag acc0 = ffrag{0,0,0,0};
    ffrag acc1 = ffrag{0,0,0,0};
    const unsigned short* ab = &vt[wave][m * VT_STRIDE + hq * 4];
    #pragma unroll
    for (int f = 0; f < 11; f++) {
        unsigned int plo, phi;
        asm("v_cvt_pk_bf16_f32 %0, %1, %2" : "=v"(plo) : "v"(s[f][0]), "v"(s[f][1]));
        asm("v_cvt_pk_bf16_f32 %0, %1, %2" : "=v"(phi) : "v"(s[f][2]), "v"(s[f][3]));
        u32x2 pb; pb.x = plo; pb.y = phi;
        u32x2 av0 = *(const u32x2*)&ab[f * 16];
        u32x2 av1 = *(const u32x2*)&ab[16 * VT_STRIDE + f * 16];
        asm("v_mfma_f32_16x16x16_bf16 %0, %1, %2, %0" : "+v"(acc0) : "v"(av0), "v"(pb));
        asm("v_mfma_f32_16x16x16_bf16 %0, %1, %2, %0" : "+v"(acc1) : "v"(av1), "v"(pb));
    }

    // ---- normalize O, convert to bf16 B-fragments ----
    unsigned int af0, af1, af2, af3;
    {
        float a0 = acc0[0] * inv, a1 = acc0[1] * inv, a2 = acc0[2] * inv, a3 = acc0[3] * inv;
        asm("v_cvt_pk_bf16_f32 %0, %1, %2" : "=v"(af0) : "v"(a0), "v"(a1));
        asm("v_cvt_pk_bf16_f32 %0, %1, %2" : "=v"(af1) : "v"(a2), "v"(a3));
        float b0 = acc1[0] * inv, b1 = acc1[1] * inv, b2 = acc1[2] * inv, b3 = acc1[3] * inv;
        asm("v_cvt_pk_bf16_f32 %0, %1, %2" : "=v"(af2) : "v"(b0), "v"(b1));
        asm("v_cvt_pk_bf16_f32 %0, %1, %2" : "=v"(af3) : "v"(b2), "v"(b3));
    }
    __syncthreads();   // all waves done reading vt -> safe to overlay os
    {
        unsigned int* osl = os + (wave * 64 + lane) * 6;
        u32x2 w0; w0.x = af0; w0.y = af1;
        u32x2 w1; w1.x = af2; w1.y = af3;
        *(u32x2*)osl = w0;
        *(u32x2*)(osl + 2) = w1;
    }
    __syncthreads();

    // ---- proj: wave computes c_out block [wave*32, wave*32+32) over cin=128 ----
    ffrag pacc0 = ffrag{0,0,0,0};
    ffrag pacc1 = ffrag{0,0,0,0};
    int cA = wave * 32;
    int cB = cA + 16;
    #pragma unroll
    for (int cb2 = 0; cb2 < 8; cb2++) {
        int wsrc = cb2 >> 1, half = cb2 & 1;
        u32x2 bfr = *(const u32x2*)(os + (wsrc * 64 + hq * 16 + m) * 6 + half * 2);
        float4 wa = *(const float4*)&pw[(size_t)(cA + m) * 128 + cb2 * 16 + hq * 4];
        float4 wb = *(const float4*)&pw[(size_t)(cB + m) * 128 + cb2 * 16 + hq * 4];
        unsigned int a0, a1, b0, b1;
        asm("v_cvt_pk_bf16_f32 %0, %1, %2" : "=v"(a0) : "v"(wa.x), "v"(wa.y));
        asm("v_cvt_pk_bf16_f32 %0, %1, %2" : "=v"(a1) : "v"(wa.z), "v"(wa.w));
        asm("v_cvt_pk_bf16_f32 %0, %1, %2" : "=v"(b0) : "v"(wb.x), "v"(wb.y));
        asm("v_cvt_pk_bf16_f32 %0, %1, %2" : "=v"(b1) : "v"(wb.z), "v"(wb.w));
        u32x2 awA; awA.x = a0; awA.y = a1;
        u32x2 awB; awB.x = b0; awB.y = b1;
        asm("v_mfma_f32_16x16x16_bf16 %0, %1, %2, %0" : "+v"(pacc0) : "v"(awA), "v"(bfr));
        asm("v_mfma_f32_16x16x16_bf16 %0, %1, %2, %0" : "+v"(pacc1) : "v"(awB), "v"(bfr));
    }

    // ---- epilogue: bias + residual, store (C, N) fp32 ----
    #pragma unroll
    for (int r = 0; r < 4; r++) {
        int c0 = cA + hq * 4 + r;
        int c1 = cB + hq * 4 + r;
        size_t i0 = (size_t)c0 * N_VOX + vox0 + m;
        size_t i1 = (size_t)c1 * N_VOX + vox0 + m;
        out[i0] = pacc0[r] + pbias[c0] + xres[i0];
        out[i1] = pacc1[r] + pbias[c1] + xres[i1];
    }
}

extern "C" void kernel_launch(void* const* d_in, const int* in_sizes, int n_in,
                              void* d_out, int out_size, void* d_ws, size_t ws_size,
                              hipStream_t stream) {
    const float* x      = (const float*)d_in[0];
    const float* gamma  = (const float*)d_in[1];
    const float* beta   = (const float*)d_in[2];
    const float* qkv_w  = (const float*)d_in[3];
    const float* qkv_b  = (const float*)d_in[4];
    const float* proj_w = (const float*)d_in[5];
    const float* proj_b = (const float*)d_in[6];
    float* out = (float*)d_out;

    unsigned short* qkv = (unsigned short*)d_ws;    // 24 MB

    hipLaunchKernelGGL(ln_qkv, dim3(2, 512), dim3(256), 0, stream,
                       x, gamma, beta, qkv_w, qkv_b, qkv);
    const unsigned short* qb = qkv;
    const unsigned short* kb = qkv + (size_t)N_VOX * 128;
    const unsigned short* vb = qkv + (size_t)2 * N_VOX * 128;
    hipLaunchKernelGGL(attn_proj, dim3(2048), dim3(256), 0, stream,
                       qb, kb, vb, proj_w, proj_b, x, out);
}